// Round 9
// baseline (194.204 us; speedup 1.0000x reference)
//
#include <hip/hip_runtime.h>
#include <hip/hip_bf16.h>

typedef __attribute__((ext_vector_type(8))) short short8;
typedef __attribute__((ext_vector_type(4))) float f32x4;
typedef unsigned short ushort_t;

namespace {

constexpr int H     = 128;
constexpr int E     = 1000000;
constexpr int NNODE = 100000;
constexpr int EB    = 512;                   // edges per tile (8 waves x 64)
constexpr int NTILE = (E + EB - 1) / EB;     // 1954
constexpr int GRID  = 256;                   // persistent: 1 block per CU
constexpr int TPB   = NTILE / GRID;          // 7
constexpr int REM   = NTILE - TPB * GRID;    // 162 blocks do TPB+1 tiles

// d_ws layout
constexpr size_t NB_OFF  = 0;                                  // bf16 nodes: 25.6 MB
constexpr size_t W1F_OFF = (size_t)NNODE * H * 2;
constexpr size_t W1F_SZ  = 72 * 64 * 8 * 2;                    // 73728 B (K=288)
constexpr size_t W2F_OFF = W1F_OFF + W1F_SZ;
constexpr size_t W2F_SZ  = 20 * 64 * 8 * 2;                    // 20480 B (K=160)
constexpr size_t WS_NEED = W2F_OFF + W2F_SZ;

__device__ __forceinline__ ushort_t f2bf(float x) {
    unsigned u = __float_as_uint(x);
    return (ushort_t)((u + 0x7FFFu + ((u >> 16) & 1u)) >> 16);
}
__device__ __forceinline__ unsigned pkbf(float a, float b) {
    __hip_bfloat162 t = __float22bfloat162_rn(make_float2(a, b));
    return *reinterpret_cast<unsigned*>(&t);
}
__device__ __forceinline__ int imin(int a, int b) { return a < b ? a : b; }

union FragU { int4 i; short8 s; };

// ---- prep 1: node_embed fp32 -> bf16 table ----
__global__ void cvt_nodes(const float* __restrict__ src, ushort_t* __restrict__ dst, int n4) {
    int i = blockIdx.x * blockDim.x + threadIdx.x;
    int stride = gridDim.x * blockDim.x;
    for (; i < n4; i += stride) {
        float4 v = reinterpret_cast<const float4*>(src)[i];
        ushort4 o;
        o.x = f2bf(v.x); o.y = f2bf(v.y); o.z = f2bf(v.z); o.w = f2bf(v.w);
        reinterpret_cast<ushort4*>(dst)[i] = o;
    }
}

// ---- prep 2: W1ext (K=288) / W2ext (K=160) -> MFMA fragment layout ----
__global__ void cvt_wfrag(const float* __restrict__ W1, const float* __restrict__ b1,
                          const float* __restrict__ W2, const float* __restrict__ b2,
                          ushort_t* __restrict__ w1f, ushort_t* __restrict__ w2f) {
    int u = blockIdx.x, l = threadIdx.x;
    int lo = l & 15, hi = l >> 4;
    if (u < 72) {                       // W1ext: 9 K-steps x 8 N-tiles
        int s = u >> 3, n = u & 7, col = n * 16 + lo;
#pragma unroll
        for (int j = 0; j < 8; ++j) {
            int kk = s * 32 + hi * 8 + j;
            float v = (kk < 258) ? W1[kk * 128 + col]
                    : (kk == 258 ? b1[col] : 0.f);
            w1f[(u * 64 + l) * 8 + j] = f2bf(v);
        }
    } else {                            // W2ext: 5 K-steps x 4 N-tiles
        int u2 = u - 72;
        int s = u2 >> 2, n = u2 & 3, col = n * 16 + lo;
#pragma unroll
        for (int j = 0; j < 8; ++j) {
            int kk = s * 32 + hi * 8 + j;
            float v = (kk < 128) ? W2[kk * 64 + col]
                    : (kk == 128 ? b2[col] : 0.f);
            w2f[(u2 * 64 + l) * 8 + j] = f2bf(v);
        }
    }
}

// ---- main persistent kernel: 512 threads, 8 waves, 64 edges/wave ----
struct SmemT {
    ushort_t w1f[36864];     // 73728 B
    ushort_t w2f[10240];     // 20480 B
    char     hbuf[65536];    // 8 waves x 8 KB (32-edge pair buffer, fenced)
    float    gs[128], bs[128], w3s[64];
};                           // 161024 B

// gather one K-slice (4 subtiles) into a named frag buffer
#define GLOAD(dst, nodes, sl)                                                              \
    _Pragma("unroll")                                                                      \
    for (int mt_ = 0; mt_ < 4; ++mt_)                                                      \
        dst[mt_] = *reinterpret_cast<const short8*>(                                       \
            nb + (size_t)nodes[mt_] * H + (sl) * 32 + hi * 8);

// one GEMM1 K-step: 8 W-fragment reads, each feeding 4 MFMAs (setprio'd cluster)
#define KSTEP(fbuf, sidx)                                                                  \
    __builtin_amdgcn_s_setprio(1);                                                         \
    _Pragma("unroll")                                                                      \
    for (int n_ = 0; n_ < 8; ++n_) {                                                       \
        short8 wa_ = *reinterpret_cast<const short8*>(                                     \
            sm.w1f + (((sidx) * 8 + n_) * 64 + lane) * 8);                                 \
        _Pragma("unroll")                                                                  \
        for (int mt_ = 0; mt_ < 4; ++mt_)                                                  \
            acc1[mt_][n_] = __builtin_amdgcn_mfma_f32_16x16x32_bf16(                       \
                wa_, fbuf[mt_], acc1[mt_][n_], 0, 0, 0);                                   \
    }                                                                                      \
    __builtin_amdgcn_s_setprio(0);

__global__ __launch_bounds__(512, 2)
void edge_mlp_mfma(const ushort_t* __restrict__ nb,
                   const ushort_t* __restrict__ w1fg,
                   const ushort_t* __restrict__ w2fg,
                   const int*      __restrict__ eidx,   // [2][E] int32
                   const float*    __restrict__ attr,   // [E][2]
                   const float*    __restrict__ gamma_,
                   const float*    __restrict__ beta_,
                   const float*    __restrict__ W3,
                   const float*    __restrict__ b3,
                   float*          __restrict__ out) {
    __shared__ SmemT sm;
    const int tid = threadIdx.x;
    const int bid = blockIdx.x;

    // ---- stage weights/params ONCE ----
    {
        const uint4* s1 = reinterpret_cast<const uint4*>(w1fg);
        uint4*       d1 = reinterpret_cast<uint4*>(sm.w1f);
        for (int i = tid; i < 4608; i += 512) d1[i] = s1[i];
        const uint4* s2 = reinterpret_cast<const uint4*>(w2fg);
        uint4*       d2 = reinterpret_cast<uint4*>(sm.w2f);
        for (int i = tid; i < 1280; i += 512) d2[i] = s2[i];
    }
    if (tid < 128) { sm.gs[tid] = gamma_[tid]; sm.bs[tid] = beta_[tid]; }
    else if (tid >= 256 && tid < 320) sm.w3s[tid - 256] = W3[tid - 256];
    __syncthreads();   // the only block-wide barrier

    const int wid = tid >> 6;
    const int lane = tid & 63;
    const int lo = lane & 15, hi = lane >> 4;
    const int ebl = wid * 64;
    const int nk = (bid < REM) ? TPB + 1 : TPB;
    char* hb = sm.hbuf + wid * 8192;
    const float2* attr2 = reinterpret_cast<const float2*>(attr);
    const float b3s = b3[0];
    const f32x4 zero4 = {0.f, 0.f, 0.f, 0.f};

    // h layout (32-edge pair buffer): element (edge e'=0..31, col) at byte
    //   (col>>5)*2048 + ((col>>3)&3)*512 + e'*16 + (col&7)*2
    const int hwb = lo * 16 + (hi & 1) * 8 + (hi >> 1) * 512;

    // ---- index state: ci/cj = tile-k indices, xi/xj = tile-(k+1) ----
    int ci[4], cj[4], xi[4], xj[4];
    {
        int tb0 = bid * EB + ebl;
#pragma unroll
        for (int mt = 0; mt < 4; ++mt) {
            int e = imin(tb0 + mt * 16 + lo, E - 1);
            ci[mt] = eidx[e]; cj[mt] = eidx[E + e];
        }
    }
    short8 f0[4], f1[4], f2[4];
    GLOAD(f0, ci, 0); GLOAD(f1, ci, 1); GLOAD(f2, ci, 2);
    {
        int tb1 = (bid + imin(1, nk - 1) * GRID) * EB + ebl;
#pragma unroll
        for (int mt = 0; mt < 4; ++mt) {
            int e = imin(tb1 + mt * 16 + lo, E - 1);
            xi[mt] = eidx[e]; xj[mt] = eidx[E + e];
        }
    }

    for (int k = 0; k < nk; ++k) {
        const int tb = (bid + k * GRID) * EB + ebl;

        float2 av[4];
#pragma unroll
        for (int mt = 0; mt < 4; ++mt)
            av[mt] = attr2[imin(tb + mt * 16 + lo, E - 1)];

        // ---- GEMM1 (swapped): acc[subtile][feat-tile], K=288, rolling gathers ----
        f32x4 acc1[4][8];
#pragma unroll
        for (int mt = 0; mt < 4; ++mt)
#pragma unroll
            for (int n = 0; n < 8; ++n) acc1[mt][n] = zero4;

        KSTEP(f0, 0); GLOAD(f0, ci, 3);
        KSTEP(f1, 1); GLOAD(f1, cj, 0);
        KSTEP(f2, 2); GLOAD(f2, cj, 1);
        KSTEP(f0, 3); GLOAD(f0, cj, 2);
        KSTEP(f1, 4); GLOAD(f1, cj, 3);
        KSTEP(f2, 5);
        KSTEP(f0, 6);
        KSTEP(f1, 7);
        {   // K-step 8: attr0, attr1, bias(1.0) rows
            FragU fa[4];
#pragma unroll
            for (int mt = 0; mt < 4; ++mt)
                fa[mt].i = make_int4(hi == 0 ? (int)pkbf(av[mt].x, av[mt].y) : 0,
                                     hi == 0 ? 0x3F80 : 0, 0, 0);
            __builtin_amdgcn_s_setprio(1);
#pragma unroll
            for (int n = 0; n < 8; ++n) {
                short8 wa = *reinterpret_cast<const short8*>(sm.w1f + ((64 + n) * 64 + lane) * 8);
#pragma unroll
                for (int mt = 0; mt < 4; ++mt)
                    acc1[mt][n] = __builtin_amdgcn_mfma_f32_16x16x32_bf16(wa, fa[mt].s, acc1[mt][n], 0, 0, 0);
            }
            __builtin_amdgcn_s_setprio(0);
        }

        // ---- rotate indices; issue next tile's first gather slices now ----
#pragma unroll
        for (int mt = 0; mt < 4; ++mt) { ci[mt] = xi[mt]; cj[mt] = xj[mt]; }
        GLOAD(f0, ci, 0); GLOAD(f1, ci, 1); GLOAD(f2, ci, 2);
        {
            int t2 = imin(k + 2, nk - 1);
            int tb2 = (bid + t2 * GRID) * EB + ebl;
#pragma unroll
            for (int mt = 0; mt < 4; ++mt) {
                int e = imin(tb2 + mt * 16 + lo, E - 1);
                xi[mt] = eidx[e]; xj[mt] = eidx[E + e];
            }
        }

        // ---- batched LN stats for all 4 subtiles (shuffle chains overlap) ----
        float mean[4], rstd[4];
#pragma unroll
        for (int mtl = 0; mtl < 4; ++mtl) {
            float s1 = 0.f, s2 = 0.f;
#pragma unroll
            for (int n = 0; n < 8; ++n)
#pragma unroll
                for (int r = 0; r < 4; ++r) {
                    float x = acc1[mtl][n][r];
                    s1 += x; s2 = fmaf(x, x, s2);
                }
            s1 += __shfl_xor(s1, 16); s1 += __shfl_xor(s1, 32);
            s2 += __shfl_xor(s2, 16); s2 += __shfl_xor(s2, 32);
            float mu = s1 * (1.f / 128.f);
            float var = s2 * (1.f / 128.f) - mu * mu;
            mean[mtl] = mu;
            rstd[mtl] = rsqrtf(var + 1e-5f);
        }

        // ---- phase 2: two 32-edge pairs; h-write fused with GEMM2 per K-step ----
#pragma unroll
        for (int p = 0; p < 2; ++p) {
            // WAR fence vs previous pair's hf reads (rule #18: pin with sched_barrier)
            asm volatile("s_waitcnt lgkmcnt(0)" ::: "memory");
            __builtin_amdgcn_sched_barrier(0);

            f32x4 a2[2][4];
#pragma unroll
            for (int X = 0; X < 2; ++X)
#pragma unroll
                for (int n2 = 0; n2 < 4; ++n2) a2[X][n2] = zero4;

#pragma unroll
            for (int s = 0; s < 4; ++s) {
                // write h for feats [32s, 32s+32), both halves; gv/bv amortized
#pragma unroll
                for (int q = 0; q < 2; ++q) {
                    const int n = 2 * s + q;
                    f32x4 gv = *reinterpret_cast<const f32x4*>(sm.gs + n * 16 + hi * 4);
                    f32x4 bv = *reinterpret_cast<const f32x4*>(sm.bs + n * 16 + hi * 4);
#pragma unroll
                    for (int half = 0; half < 2; ++half) {
                        const int mtl = p * 2 + half;
                        float h0 = fmaxf(fmaf((acc1[mtl][n][0] - mean[mtl]) * rstd[mtl], gv[0], bv[0]), 0.f);
                        float h1 = fmaxf(fmaf((acc1[mtl][n][1] - mean[mtl]) * rstd[mtl], gv[1], bv[1]), 0.f);
                        float h2 = fmaxf(fmaf((acc1[mtl][n][2] - mean[mtl]) * rstd[mtl], gv[2], bv[2]), 0.f);
                        float h3 = fmaxf(fmaf((acc1[mtl][n][3] - mean[mtl]) * rstd[mtl], gv[3], bv[3]), 0.f);
                        *reinterpret_cast<uint2*>(hb + (s * 2048 + q * 1024 + half * 256 + hwb)) =
                            make_uint2(pkbf(h0, h1), pkbf(h2, h3));
                    }
                }
                // read this K-step's A-fragments and do its MFMAs (RAW spans only 4 writes)
                short8 hf0 = *reinterpret_cast<const short8*>(hb + s * 2048 + hi * 512 + lo * 16);
                short8 hf1 = *reinterpret_cast<const short8*>(hb + s * 2048 + hi * 512 + 256 + lo * 16);
                __builtin_amdgcn_s_setprio(1);
#pragma unroll
                for (int n2 = 0; n2 < 4; ++n2) {
                    short8 wa = *reinterpret_cast<const short8*>(sm.w2f + ((s * 4 + n2) * 64 + lane) * 8);
                    a2[0][n2] = __builtin_amdgcn_mfma_f32_16x16x32_bf16(wa, hf0, a2[0][n2], 0, 0, 0);
                    a2[1][n2] = __builtin_amdgcn_mfma_f32_16x16x32_bf16(wa, hf1, a2[1][n2], 0, 0, 0);
                }
                __builtin_amdgcn_s_setprio(0);
            }
            {   // K-step 4: bias row (b2)
                FragU cf; cf.i = make_int4(hi == 0 ? 0x3F80 : 0, 0, 0, 0);
                __builtin_amdgcn_s_setprio(1);
#pragma unroll
                for (int n2 = 0; n2 < 4; ++n2) {
                    short8 wa = *reinterpret_cast<const short8*>(sm.w2f + ((16 + n2) * 64 + lane) * 8);
                    a2[0][n2] = __builtin_amdgcn_mfma_f32_16x16x32_bf16(wa, cf.s, a2[0][n2], 0, 0, 0);
                    a2[1][n2] = __builtin_amdgcn_mfma_f32_16x16x32_bf16(wa, cf.s, a2[1][n2], 0, 0, 0);
                }
                __builtin_amdgcn_s_setprio(0);
            }

            // epilogue: relu, dot W3 (w3v amortized across X), cross-hi reduce, store
            float part0 = 0.f, part1 = 0.f;
#pragma unroll
            for (int n2 = 0; n2 < 4; ++n2) {
                f32x4 w3v = *reinterpret_cast<const f32x4*>(sm.w3s + n2 * 16 + hi * 4);
#pragma unroll
                for (int r = 0; r < 4; ++r) {
                    part0 = fmaf(fmaxf(a2[0][n2][r], 0.f), w3v[r], part0);
                    part1 = fmaf(fmaxf(a2[1][n2][r], 0.f), w3v[r], part1);
                }
            }
            part0 += __shfl_xor(part0, 16); part0 += __shfl_xor(part0, 32);
            part1 += __shfl_xor(part1, 16); part1 += __shfl_xor(part1, 32);
            if (hi == 0) {
                int e0 = tb + (p * 2 + 0) * 16 + lo;
                int e1 = tb + (p * 2 + 1) * 16 + lo;
                if (e0 < E) out[e0] = part0 + b3s;
                if (e1 < E) out[e1] = part1 + b3s;
            }
        }
    }
}

} // namespace

extern "C" void kernel_launch(void* const* d_in, const int* in_sizes, int n_in,
                              void* d_out, int out_size, void* d_ws, size_t ws_size,
                              hipStream_t stream) {
    const float* node_embed = (const float*)d_in[0];
    const int*   eidx       = (const int*)  d_in[1];
    const float* attr       = (const float*)d_in[2];
    const float* W1         = (const float*)d_in[3];
    const float* b1         = (const float*)d_in[4];
    const float* gamma      = (const float*)d_in[5];
    const float* beta       = (const float*)d_in[6];
    const float* W2         = (const float*)d_in[7];
    const float* b2         = (const float*)d_in[8];
    const float* W3         = (const float*)d_in[9];
    const float* b3         = (const float*)d_in[10];
    float* out = (float*)d_out;

    if (ws_size < WS_NEED) return;

    char* ws = (char*)d_ws;
    ushort_t* nbf = (ushort_t*)(ws + NB_OFF);
    ushort_t* w1f = (ushort_t*)(ws + W1F_OFF);
    ushort_t* w2f = (ushort_t*)(ws + W2F_OFF);

    cvt_nodes<<<2048, 256, 0, stream>>>(node_embed, nbf, NNODE * H / 4);
    cvt_wfrag<<<92, 64, 0, stream>>>(W1, b1, W2, b2, w1f, w2f);
    edge_mlp_mfma<<<GRID, 512, 0, stream>>>(nbf, w1f, w2f, eidx, attr,
                                            gamma, beta, W3, b3, out);
}

// Round 10
// 159.057 us; speedup vs baseline: 1.2210x; 1.2210x over previous
//
#include <hip/hip_runtime.h>
#include <hip/hip_bf16.h>

typedef __attribute__((ext_vector_type(8))) short short8;
typedef __attribute__((ext_vector_type(4))) float f32x4;
typedef unsigned short ushort_t;

namespace {

constexpr int H     = 128;
constexpr int E     = 1000000;
constexpr int NNODE = 100000;
constexpr int EB    = 512;                   // edges per tile (8 waves x 64)
constexpr int NTILE = (E + EB - 1) / EB;     // 1954
constexpr int GRID  = 256;                   // persistent: 1 block per CU
constexpr int TPB   = NTILE / GRID;          // 7
constexpr int REM   = NTILE - TPB * GRID;    // 162 blocks do TPB+1 tiles

// d_ws layout
constexpr size_t NB_OFF  = 0;                                  // bf16 nodes: 25.6 MB
constexpr size_t W1F_OFF = (size_t)NNODE * H * 2;
constexpr size_t W1F_SZ  = 72 * 64 * 8 * 2;                    // 73728 B (K=288)
constexpr size_t W2F_OFF = W1F_OFF + W1F_SZ;
constexpr size_t W2F_SZ  = 20 * 64 * 8 * 2;                    // 20480 B (K=160)
constexpr size_t WS_NEED = W2F_OFF + W2F_SZ;

__device__ __forceinline__ ushort_t f2bf(float x) {
    unsigned u = __float_as_uint(x);
    return (ushort_t)((u + 0x7FFFu + ((u >> 16) & 1u)) >> 16);
}
__device__ __forceinline__ unsigned pkbf(float a, float b) {
    __hip_bfloat162 t = __float22bfloat162_rn(make_float2(a, b));
    return *reinterpret_cast<unsigned*>(&t);
}
__device__ __forceinline__ int imin(int a, int b) { return a < b ? a : b; }

union FragU { int4 i; short8 s; };

// ---- prep 1: node_embed fp32 -> bf16 table ----
__global__ void cvt_nodes(const float* __restrict__ src, ushort_t* __restrict__ dst, int n4) {
    int i = blockIdx.x * blockDim.x + threadIdx.x;
    int stride = gridDim.x * blockDim.x;
    for (; i < n4; i += stride) {
        float4 v = reinterpret_cast<const float4*>(src)[i];
        ushort4 o;
        o.x = f2bf(v.x); o.y = f2bf(v.y); o.z = f2bf(v.z); o.w = f2bf(v.w);
        reinterpret_cast<ushort4*>(dst)[i] = o;
    }
}

// ---- prep 2: W1ext (K=288) / W2ext (K=160) -> MFMA fragment layout ----
__global__ void cvt_wfrag(const float* __restrict__ W1, const float* __restrict__ b1,
                          const float* __restrict__ W2, const float* __restrict__ b2,
                          ushort_t* __restrict__ w1f, ushort_t* __restrict__ w2f) {
    int u = blockIdx.x, l = threadIdx.x;
    int lo = l & 15, hi = l >> 4;
    if (u < 72) {                       // W1ext: 9 K-steps x 8 N-tiles
        int s = u >> 3, n = u & 7, col = n * 16 + lo;
#pragma unroll
        for (int j = 0; j < 8; ++j) {
            int kk = s * 32 + hi * 8 + j;
            float v = (kk < 258) ? W1[kk * 128 + col]
                    : (kk == 258 ? b1[col] : 0.f);
            w1f[(u * 64 + l) * 8 + j] = f2bf(v);
        }
    } else {                            // W2ext: 5 K-steps x 4 N-tiles
        int u2 = u - 72;
        int s = u2 >> 2, n = u2 & 3, col = n * 16 + lo;
#pragma unroll
        for (int j = 0; j < 8; ++j) {
            int kk = s * 32 + hi * 8 + j;
            float v = (kk < 128) ? W2[kk * 64 + col]
                    : (kk == 128 ? b2[col] : 0.f);
            w2f[(u2 * 64 + l) * 8 + j] = f2bf(v);
        }
    }
}

// ---- main persistent kernel: 512 threads, 8 waves, 64 edges/wave ----
struct SmemT {
    ushort_t w1f[36864];     // 73728 B
    ushort_t w2f[10240];     // 20480 B
    char     hbuf[65536];    // 8 waves x 8 KB (32-edge pair buffer, fenced)
    float    gs[128], bs[128], w3s[64];
};                           // 161024 B

// gather one K-slice (4 subtiles) into a named frag buffer
#define GLOAD(dst, nodes, sl)                                                              \
    _Pragma("unroll")                                                                      \
    for (int mt_ = 0; mt_ < 4; ++mt_)                                                      \
        dst[mt_] = *reinterpret_cast<const short8*>(                                       \
            nb + (size_t)nodes[mt_] * H + (sl) * 32 + hi * 8);

// one GEMM1 K-step: 8 W-fragment reads, each feeding 4 MFMAs (setprio'd cluster)
#define KSTEP(fbuf, sidx)                                                                  \
    __builtin_amdgcn_s_setprio(1);                                                         \
    _Pragma("unroll")                                                                      \
    for (int n_ = 0; n_ < 8; ++n_) {                                                       \
        short8 wa_ = *reinterpret_cast<const short8*>(                                     \
            sm.w1f + (((sidx) * 8 + n_) * 64 + lane) * 8);                                 \
        _Pragma("unroll")                                                                  \
        for (int mt_ = 0; mt_ < 4; ++mt_)                                                  \
            acc1[mt_][n_] = __builtin_amdgcn_mfma_f32_16x16x32_bf16(                       \
                wa_, fbuf[mt_], acc1[mt_][n_], 0, 0, 0);                                   \
    }                                                                                      \
    __builtin_amdgcn_s_setprio(0);

__global__ __launch_bounds__(512, 2)
void edge_mlp_mfma(const ushort_t* __restrict__ nb,
                   const ushort_t* __restrict__ w1fg,
                   const ushort_t* __restrict__ w2fg,
                   const int*      __restrict__ eidx,   // [2][E] int32
                   const float*    __restrict__ attr,   // [E][2]
                   const float*    __restrict__ gamma_,
                   const float*    __restrict__ beta_,
                   const float*    __restrict__ W3,
                   const float*    __restrict__ b3,
                   float*          __restrict__ out) {
    __shared__ SmemT sm;
    const int tid = threadIdx.x;
    const int bid = blockIdx.x;

    // ---- stage weights/params ONCE ----
    {
        const uint4* s1 = reinterpret_cast<const uint4*>(w1fg);
        uint4*       d1 = reinterpret_cast<uint4*>(sm.w1f);
        for (int i = tid; i < 4608; i += 512) d1[i] = s1[i];
        const uint4* s2 = reinterpret_cast<const uint4*>(w2fg);
        uint4*       d2 = reinterpret_cast<uint4*>(sm.w2f);
        for (int i = tid; i < 1280; i += 512) d2[i] = s2[i];
    }
    if (tid < 128) { sm.gs[tid] = gamma_[tid]; sm.bs[tid] = beta_[tid]; }
    else if (tid >= 256 && tid < 320) sm.w3s[tid - 256] = W3[tid - 256];
    __syncthreads();   // the only block-wide barrier

    const int wid = tid >> 6;
    const int lane = tid & 63;
    const int lo = lane & 15, hi = lane >> 4;
    const int ebl = wid * 64;
    const int nk = (bid < REM) ? TPB + 1 : TPB;
    char* hb = sm.hbuf + wid * 8192;
    const float2* attr2 = reinterpret_cast<const float2*>(attr);
    const float b3s = b3[0];
    const f32x4 zero4 = {0.f, 0.f, 0.f, 0.f};

    // h layout (32-edge pair buffer): element (edge e'=0..31, col) at byte
    //   (col>>5)*2048 + ((col>>3)&3)*512 + e'*16 + (col&7)*2
    const int hwb = lo * 16 + (hi & 1) * 8 + (hi >> 1) * 512;

    // ---- index state: ci/cj = tile-k indices, xi/xj = tile-(k+1) ----
    int ci[4], cj[4], xi[4], xj[4];
    {
        int tb0 = bid * EB + ebl;
#pragma unroll
        for (int mt = 0; mt < 4; ++mt) {
            int e = imin(tb0 + mt * 16 + lo, E - 1);
            ci[mt] = eidx[e]; cj[mt] = eidx[E + e];
        }
    }
    short8 f0[4], f1[4], f2[4];
    GLOAD(f0, ci, 0); GLOAD(f1, ci, 1); GLOAD(f2, ci, 2);
    {
        int tb1 = (bid + imin(1, nk - 1) * GRID) * EB + ebl;
#pragma unroll
        for (int mt = 0; mt < 4; ++mt) {
            int e = imin(tb1 + mt * 16 + lo, E - 1);
            xi[mt] = eidx[e]; xj[mt] = eidx[E + e];
        }
    }

    for (int k = 0; k < nk; ++k) {
        const int tb = (bid + k * GRID) * EB + ebl;

        float2 av[4];
#pragma unroll
        for (int mt = 0; mt < 4; ++mt)
            av[mt] = attr2[imin(tb + mt * 16 + lo, E - 1)];

        // ---- GEMM1 (swapped): acc[subtile][feat-tile], K=288, rolling gathers ----
        f32x4 acc1[4][8];
#pragma unroll
        for (int mt = 0; mt < 4; ++mt)
#pragma unroll
            for (int n = 0; n < 8; ++n) acc1[mt][n] = zero4;

        KSTEP(f0, 0); GLOAD(f0, ci, 3);
        KSTEP(f1, 1); GLOAD(f1, cj, 0);
        KSTEP(f2, 2); GLOAD(f2, cj, 1);
        KSTEP(f0, 3); GLOAD(f0, cj, 2);
        KSTEP(f1, 4); GLOAD(f1, cj, 3);
        KSTEP(f2, 5);
        KSTEP(f0, 6);
        KSTEP(f1, 7);
        {   // K-step 8: attr0, attr1, bias(1.0) rows
            FragU fa[4];
#pragma unroll
            for (int mt = 0; mt < 4; ++mt)
                fa[mt].i = make_int4(hi == 0 ? (int)pkbf(av[mt].x, av[mt].y) : 0,
                                     hi == 0 ? 0x3F80 : 0, 0, 0);
            __builtin_amdgcn_s_setprio(1);
#pragma unroll
            for (int n = 0; n < 8; ++n) {
                short8 wa = *reinterpret_cast<const short8*>(sm.w1f + ((64 + n) * 64 + lane) * 8);
#pragma unroll
                for (int mt = 0; mt < 4; ++mt)
                    acc1[mt][n] = __builtin_amdgcn_mfma_f32_16x16x32_bf16(wa, fa[mt].s, acc1[mt][n], 0, 0, 0);
            }
            __builtin_amdgcn_s_setprio(0);
        }

        // ---- rotate indices; issue next tile's first gather slices now ----
#pragma unroll
        for (int mt = 0; mt < 4; ++mt) { ci[mt] = xi[mt]; cj[mt] = xj[mt]; }
        GLOAD(f0, ci, 0); GLOAD(f1, ci, 1); GLOAD(f2, ci, 2);
        {
            int t2 = imin(k + 2, nk - 1);
            int tb2 = (bid + t2 * GRID) * EB + ebl;
#pragma unroll
            for (int mt = 0; mt < 4; ++mt) {
                int e = imin(tb2 + mt * 16 + lo, E - 1);
                xi[mt] = eidx[e]; xj[mt] = eidx[E + e];
            }
        }

        // ---- phase 2: two 32-edge pairs (R8 structure: write-all-h, then GEMM2) ----
#pragma unroll
        for (int p = 0; p < 2; ++p) {
            // WAR fence: previous pair's GEMM2 ds_reads must complete before
            // overwriting the shared h buffer (rule #18: pin with sched_barrier).
            asm volatile("s_waitcnt lgkmcnt(0)" ::: "memory");
            __builtin_amdgcn_sched_barrier(0);

            // LN stats for this pair's two halves (chains overlap; +4 regs only)
            float mean[2], rstd[2];
#pragma unroll
            for (int half = 0; half < 2; ++half) {
                const int mtl = p * 2 + half;
                float s1 = 0.f, s2 = 0.f;
#pragma unroll
                for (int n = 0; n < 8; ++n)
#pragma unroll
                    for (int r = 0; r < 4; ++r) {
                        float x = acc1[mtl][n][r];
                        s1 += x; s2 = fmaf(x, x, s2);
                    }
                s1 += __shfl_xor(s1, 16); s1 += __shfl_xor(s1, 32);
                s2 += __shfl_xor(s2, 16); s2 += __shfl_xor(s2, 32);
                float mu = s1 * (1.f / 128.f);
                float var = s2 * (1.f / 128.f) - mu * mu;
                mean[half] = mu;
                rstd[half] = rsqrtf(var + 1e-5f);
            }

            // h-writes: n outer so gv/bv amortize across the two halves
#pragma unroll
            for (int n = 0; n < 8; ++n) {
                f32x4 gv = *reinterpret_cast<const f32x4*>(sm.gs + n * 16 + hi * 4);
                f32x4 bv = *reinterpret_cast<const f32x4*>(sm.bs + n * 16 + hi * 4);
#pragma unroll
                for (int half = 0; half < 2; ++half) {
                    const int mtl = p * 2 + half;
                    float h0 = fmaxf(fmaf((acc1[mtl][n][0] - mean[half]) * rstd[half], gv[0], bv[0]), 0.f);
                    float h1 = fmaxf(fmaf((acc1[mtl][n][1] - mean[half]) * rstd[half], gv[1], bv[1]), 0.f);
                    float h2 = fmaxf(fmaf((acc1[mtl][n][2] - mean[half]) * rstd[half], gv[2], bv[2]), 0.f);
                    float h3 = fmaxf(fmaf((acc1[mtl][n][3] - mean[half]) * rstd[half], gv[3], bv[3]), 0.f);
                    *reinterpret_cast<uint2*>(hb + ((n >> 1) * 2048 + (n & 1) * 1024
                                                    + half * 256 + hwb)) =
                        make_uint2(pkbf(h0, h1), pkbf(h2, h3));
                }
            }

            // GEMM2 (swapped) on the 32-edge pair: each w2f read feeds 2 MFMAs
            f32x4 a2[2][4];
#pragma unroll
            for (int X = 0; X < 2; ++X)
#pragma unroll
                for (int n2 = 0; n2 < 4; ++n2) a2[X][n2] = zero4;

#pragma unroll
            for (int s = 0; s < 4; ++s) {
                short8 hf0 = *reinterpret_cast<const short8*>(hb + s * 2048 + hi * 512 + lo * 16);
                short8 hf1 = *reinterpret_cast<const short8*>(hb + s * 2048 + hi * 512 + 256 + lo * 16);
                __builtin_amdgcn_s_setprio(1);
#pragma unroll
                for (int n2 = 0; n2 < 4; ++n2) {
                    short8 wa = *reinterpret_cast<const short8*>(sm.w2f + ((s * 4 + n2) * 64 + lane) * 8);
                    a2[0][n2] = __builtin_amdgcn_mfma_f32_16x16x32_bf16(wa, hf0, a2[0][n2], 0, 0, 0);
                    a2[1][n2] = __builtin_amdgcn_mfma_f32_16x16x32_bf16(wa, hf1, a2[1][n2], 0, 0, 0);
                }
                __builtin_amdgcn_s_setprio(0);
            }
            {   // K-step 4: bias row (b2)
                FragU cf; cf.i = make_int4(hi == 0 ? 0x3F80 : 0, 0, 0, 0);
                __builtin_amdgcn_s_setprio(1);
#pragma unroll
                for (int n2 = 0; n2 < 4; ++n2) {
                    short8 wa = *reinterpret_cast<const short8*>(sm.w2f + ((16 + n2) * 64 + lane) * 8);
                    a2[0][n2] = __builtin_amdgcn_mfma_f32_16x16x32_bf16(wa, cf.s, a2[0][n2], 0, 0, 0);
                    a2[1][n2] = __builtin_amdgcn_mfma_f32_16x16x32_bf16(wa, cf.s, a2[1][n2], 0, 0, 0);
                }
                __builtin_amdgcn_s_setprio(0);
            }

            // epilogue: relu, dot W3 (w3v amortized across X), cross-hi reduce, store
            float part0 = 0.f, part1 = 0.f;
#pragma unroll
            for (int n2 = 0; n2 < 4; ++n2) {
                f32x4 w3v = *reinterpret_cast<const f32x4*>(sm.w3s + n2 * 16 + hi * 4);
#pragma unroll
                for (int r = 0; r < 4; ++r) {
                    part0 = fmaf(fmaxf(a2[0][n2][r], 0.f), w3v[r], part0);
                    part1 = fmaf(fmaxf(a2[1][n2][r], 0.f), w3v[r], part1);
                }
            }
            part0 += __shfl_xor(part0, 16); part0 += __shfl_xor(part0, 32);
            part1 += __shfl_xor(part1, 16); part1 += __shfl_xor(part1, 32);
            if (hi == 0) {
                int e0 = tb + (p * 2 + 0) * 16 + lo;
                int e1 = tb + (p * 2 + 1) * 16 + lo;
                if (e0 < E) out[e0] = part0 + b3s;
                if (e1 < E) out[e1] = part1 + b3s;
            }
        }
    }
}

} // namespace

extern "C" void kernel_launch(void* const* d_in, const int* in_sizes, int n_in,
                              void* d_out, int out_size, void* d_ws, size_t ws_size,
                              hipStream_t stream) {
    const float* node_embed = (const float*)d_in[0];
    const int*   eidx       = (const int*)  d_in[1];
    const float* attr       = (const float*)d_in[2];
    const float* W1         = (const float*)d_in[3];
    const float* b1         = (const float*)d_in[4];
    const float* gamma      = (const float*)d_in[5];
    const float* beta       = (const float*)d_in[6];
    const float* W2         = (const float*)d_in[7];
    const float* b2         = (const float*)d_in[8];
    const float* W3         = (const float*)d_in[9];
    const float* b3         = (const float*)d_in[10];
    float* out = (float*)d_out;

    if (ws_size < WS_NEED) return;

    char* ws = (char*)d_ws;
    ushort_t* nbf = (ushort_t*)(ws + NB_OFF);
    ushort_t* w1f = (ushort_t*)(ws + W1F_OFF);
    ushort_t* w2f = (ushort_t*)(ws + W2F_OFF);

    cvt_nodes<<<2048, 256, 0, stream>>>(node_embed, nbf, NNODE * H / 4);
    cvt_wfrag<<<92, 64, 0, stream>>>(W1, b1, W2, b2, w1f, w2f);
    edge_mlp_mfma<<<GRID, 512, 0, stream>>>(nbf, w1f, w2f, eidx, attr,
                                            gamma, beta, W3, b3, out);
}

// Round 11
// 158.936 us; speedup vs baseline: 1.2219x; 1.0008x over previous
//
#include <hip/hip_runtime.h>
#include <hip/hip_bf16.h>

typedef __attribute__((ext_vector_type(8))) short short8;
typedef __attribute__((ext_vector_type(4))) float f32x4;
typedef unsigned short ushort_t;

namespace {

constexpr int H     = 128;
constexpr int E     = 1000000;
constexpr int NNODE = 100000;
constexpr int EB    = 512;                   // edges per tile (8 waves x 64)
constexpr int NTILE = (E + EB - 1) / EB;     // 1954
constexpr int GRID  = 256;                   // persistent: 1 block per CU
constexpr int TPB   = NTILE / GRID;          // 7
constexpr int REM   = NTILE - TPB * GRID;    // 162 blocks do TPB+1 tiles

// d_ws layout
constexpr size_t NB_OFF  = 0;                                  // bf16 nodes: 25.6 MB
constexpr size_t W1F_OFF = (size_t)NNODE * H * 2;
constexpr size_t W1F_SZ  = 72 * 64 * 8 * 2;                    // 73728 B (K=288)
constexpr size_t W2F_OFF = W1F_OFF + W1F_SZ;
constexpr size_t W2F_SZ  = 20 * 64 * 8 * 2;                    // 20480 B (K=160)
constexpr size_t WS_NEED = W2F_OFF + W2F_SZ;

__device__ __forceinline__ ushort_t f2bf(float x) {
    unsigned u = __float_as_uint(x);
    return (ushort_t)((u + 0x7FFFu + ((u >> 16) & 1u)) >> 16);
}
__device__ __forceinline__ unsigned pkbf(float a, float b) {
    __hip_bfloat162 t = __float22bfloat162_rn(make_float2(a, b));
    return *reinterpret_cast<unsigned*>(&t);
}
__device__ __forceinline__ int imin(int a, int b) { return a < b ? a : b; }

union FragU { int4 i; short8 s; };

// ---- prep 1: node_embed fp32 -> bf16 table ----
__global__ void cvt_nodes(const float* __restrict__ src, ushort_t* __restrict__ dst, int n4) {
    int i = blockIdx.x * blockDim.x + threadIdx.x;
    int stride = gridDim.x * blockDim.x;
    for (; i < n4; i += stride) {
        float4 v = reinterpret_cast<const float4*>(src)[i];
        ushort4 o;
        o.x = f2bf(v.x); o.y = f2bf(v.y); o.z = f2bf(v.z); o.w = f2bf(v.w);
        reinterpret_cast<ushort4*>(dst)[i] = o;
    }
}

// ---- prep 2: W1ext (K=288) / W2ext (K=160) -> MFMA fragment layout ----
__global__ void cvt_wfrag(const float* __restrict__ W1, const float* __restrict__ b1,
                          const float* __restrict__ W2, const float* __restrict__ b2,
                          ushort_t* __restrict__ w1f, ushort_t* __restrict__ w2f) {
    int u = blockIdx.x, l = threadIdx.x;
    int lo = l & 15, hi = l >> 4;
    if (u < 72) {                       // W1ext: 9 K-steps x 8 N-tiles
        int s = u >> 3, n = u & 7, col = n * 16 + lo;
#pragma unroll
        for (int j = 0; j < 8; ++j) {
            int kk = s * 32 + hi * 8 + j;
            float v = (kk < 258) ? W1[kk * 128 + col]
                    : (kk == 258 ? b1[col] : 0.f);
            w1f[(u * 64 + l) * 8 + j] = f2bf(v);
        }
    } else {                            // W2ext: 5 K-steps x 4 N-tiles
        int u2 = u - 72;
        int s = u2 >> 2, n = u2 & 3, col = n * 16 + lo;
#pragma unroll
        for (int j = 0; j < 8; ++j) {
            int kk = s * 32 + hi * 8 + j;
            float v = (kk < 128) ? W2[kk * 64 + col]
                    : (kk == 128 ? b2[col] : 0.f);
            w2f[(u2 * 64 + l) * 8 + j] = f2bf(v);
        }
    }
}

// ---- main persistent kernel: 512 threads, 8 waves, 64 edges/wave ----
struct SmemT {
    ushort_t w1f[36864];     // 73728 B
    ushort_t w2f[10240];     // 20480 B
    char     hbuf[65536];    // 8 waves x 8 KB (32-edge pair buffer, fenced)
    float    gs[128], bs[128], w3s[64];
};                           // 161024 B

// VMEM-pin: everything except VMEM/VMEM_READ may cross; the gather loads may not
// be sunk to their use sites (forces early issue + long live range, late vmcnt).
#define VPIN() __builtin_amdgcn_sched_barrier(0x38F)

// gather one K-slice (4 subtiles) into a named frag buffer, pinned at issue point
#define GLOAD(dst, nodes, sl)                                                              \
    _Pragma("unroll")                                                                      \
    for (int mt_ = 0; mt_ < 4; ++mt_)                                                      \
        dst[mt_] = *reinterpret_cast<const short8*>(                                       \
            nb + (size_t)nodes[mt_] * H + (sl) * 32 + hi * 8);                             \
    VPIN();

// one GEMM1 K-step: 8 W-fragment reads, each feeding 4 MFMAs (setprio'd cluster)
#define KSTEP(fbuf, sidx)                                                                  \
    __builtin_amdgcn_s_setprio(1);                                                         \
    _Pragma("unroll")                                                                      \
    for (int n_ = 0; n_ < 8; ++n_) {                                                       \
        short8 wa_ = *reinterpret_cast<const short8*>(                                     \
            sm.w1f + (((sidx) * 8 + n_) * 64 + lane) * 8);                                 \
        _Pragma("unroll")                                                                  \
        for (int mt_ = 0; mt_ < 4; ++mt_)                                                  \
            acc1[mt_][n_] = __builtin_amdgcn_mfma_f32_16x16x32_bf16(                       \
                wa_, fbuf[mt_], acc1[mt_][n_], 0, 0, 0);                                   \
    }                                                                                      \
    __builtin_amdgcn_s_setprio(0);

__global__ __launch_bounds__(512, 2)
void edge_mlp_mfma(const ushort_t* __restrict__ nb,
                   const ushort_t* __restrict__ w1fg,
                   const ushort_t* __restrict__ w2fg,
                   const int*      __restrict__ eidx,   // [2][E] int32
                   const float*    __restrict__ attr,   // [E][2]
                   const float*    __restrict__ gamma_,
                   const float*    __restrict__ beta_,
                   const float*    __restrict__ W3,
                   const float*    __restrict__ b3,
                   float*          __restrict__ out) {
    __shared__ SmemT sm;
    const int tid = threadIdx.x;
    const int bid = blockIdx.x;

    // ---- stage weights/params ONCE ----
    {
        const uint4* s1 = reinterpret_cast<const uint4*>(w1fg);
        uint4*       d1 = reinterpret_cast<uint4*>(sm.w1f);
        for (int i = tid; i < 4608; i += 512) d1[i] = s1[i];
        const uint4* s2 = reinterpret_cast<const uint4*>(w2fg);
        uint4*       d2 = reinterpret_cast<uint4*>(sm.w2f);
        for (int i = tid; i < 1280; i += 512) d2[i] = s2[i];
    }
    if (tid < 128) { sm.gs[tid] = gamma_[tid]; sm.bs[tid] = beta_[tid]; }
    else if (tid >= 256 && tid < 320) sm.w3s[tid - 256] = W3[tid - 256];
    __syncthreads();   // the only block-wide barrier

    const int wid = tid >> 6;
    const int lane = tid & 63;
    const int lo = lane & 15, hi = lane >> 4;
    const int ebl = wid * 64;
    const int nk = (bid < REM) ? TPB + 1 : TPB;
    char* hb = sm.hbuf + wid * 8192;
    const float2* attr2 = reinterpret_cast<const float2*>(attr);
    const float b3s = b3[0];
    const f32x4 zero4 = {0.f, 0.f, 0.f, 0.f};

    // h layout (32-edge pair buffer): element (edge e'=0..31, col) at byte
    //   (col>>5)*2048 + ((col>>3)&3)*512 + e'*16 + (col&7)*2
    const int hwb = lo * 16 + (hi & 1) * 8 + (hi >> 1) * 512;

    // ---- index state: ci/cj = tile-k indices, xi/xj = tile-(k+1) ----
    int ci[4], cj[4], xi[4], xj[4];
    {
        int tb0 = bid * EB + ebl;
#pragma unroll
        for (int mt = 0; mt < 4; ++mt) {
            int e = imin(tb0 + mt * 16 + lo, E - 1);
            ci[mt] = eidx[e]; cj[mt] = eidx[E + e];
        }
    }
    short8 f0[4], f1[4], f2[4];
    GLOAD(f0, ci, 0); GLOAD(f1, ci, 1); GLOAD(f2, ci, 2);
    {
        int tb1 = (bid + imin(1, nk - 1) * GRID) * EB + ebl;
#pragma unroll
        for (int mt = 0; mt < 4; ++mt) {
            int e = imin(tb1 + mt * 16 + lo, E - 1);
            xi[mt] = eidx[e]; xj[mt] = eidx[E + e];
        }
    }

    for (int k = 0; k < nk; ++k) {
        const int tb = (bid + k * GRID) * EB + ebl;

        float2 av[4];
#pragma unroll
        for (int mt = 0; mt < 4; ++mt)
            av[mt] = attr2[imin(tb + mt * 16 + lo, E - 1)];
        VPIN();

        // ---- GEMM1 (swapped): acc[subtile][feat-tile], K=288, rolling gathers ----
        f32x4 acc1[4][8];
#pragma unroll
        for (int mt = 0; mt < 4; ++mt)
#pragma unroll
            for (int n = 0; n < 8; ++n) acc1[mt][n] = zero4;

        KSTEP(f0, 0); GLOAD(f0, ci, 3);
        KSTEP(f1, 1); GLOAD(f1, cj, 0);
        KSTEP(f2, 2); GLOAD(f2, cj, 1);
        KSTEP(f0, 3); GLOAD(f0, cj, 2);
        KSTEP(f1, 4); GLOAD(f1, cj, 3);
        KSTEP(f2, 5);
        KSTEP(f0, 6);
        KSTEP(f1, 7);
        {   // K-step 8: attr0, attr1, bias(1.0) rows
            FragU fa[4];
#pragma unroll
            for (int mt = 0; mt < 4; ++mt)
                fa[mt].i = make_int4(hi == 0 ? (int)pkbf(av[mt].x, av[mt].y) : 0,
                                     hi == 0 ? 0x3F80 : 0, 0, 0);
            __builtin_amdgcn_s_setprio(1);
#pragma unroll
            for (int n = 0; n < 8; ++n) {
                short8 wa = *reinterpret_cast<const short8*>(sm.w1f + ((64 + n) * 64 + lane) * 8);
#pragma unroll
                for (int mt = 0; mt < 4; ++mt)
                    acc1[mt][n] = __builtin_amdgcn_mfma_f32_16x16x32_bf16(wa, fa[mt].s, acc1[mt][n], 0, 0, 0);
            }
            __builtin_amdgcn_s_setprio(0);
        }

        // ---- rotate indices; issue next tile's first gather slices now ----
#pragma unroll
        for (int mt = 0; mt < 4; ++mt) { ci[mt] = xi[mt]; cj[mt] = xj[mt]; }
        GLOAD(f0, ci, 0); GLOAD(f1, ci, 1); GLOAD(f2, ci, 2);
        {
            int t2 = imin(k + 2, nk - 1);
            int tb2 = (bid + t2 * GRID) * EB + ebl;
#pragma unroll
            for (int mt = 0; mt < 4; ++mt) {
                int e = imin(tb2 + mt * 16 + lo, E - 1);
                xi[mt] = eidx[e]; xj[mt] = eidx[E + e];
            }
            VPIN();
        }

        // ---- phase 2: two 32-edge pairs (write-all-h, then GEMM2) ----
#pragma unroll
        for (int p = 0; p < 2; ++p) {
            // WAR fence: previous pair's GEMM2 ds_reads must complete before
            // overwriting the shared h buffer (rule #18: pin with sched_barrier).
            asm volatile("s_waitcnt lgkmcnt(0)" ::: "memory");
            __builtin_amdgcn_sched_barrier(0);

            // LN stats for this pair's two halves (chains overlap)
            float mean[2], rstd[2];
#pragma unroll
            for (int half = 0; half < 2; ++half) {
                const int mtl = p * 2 + half;
                float s1 = 0.f, s2 = 0.f;
#pragma unroll
                for (int n = 0; n < 8; ++n)
#pragma unroll
                    for (int r = 0; r < 4; ++r) {
                        float x = acc1[mtl][n][r];
                        s1 += x; s2 = fmaf(x, x, s2);
                    }
                s1 += __shfl_xor(s1, 16); s1 += __shfl_xor(s1, 32);
                s2 += __shfl_xor(s2, 16); s2 += __shfl_xor(s2, 32);
                float mu = s1 * (1.f / 128.f);
                float var = s2 * (1.f / 128.f) - mu * mu;
                mean[half] = mu;
                rstd[half] = rsqrtf(var + 1e-5f);
            }

            // h-writes: n outer so gv/bv amortize across the two halves
#pragma unroll
            for (int n = 0; n < 8; ++n) {
                f32x4 gv = *reinterpret_cast<const f32x4*>(sm.gs + n * 16 + hi * 4);
                f32x4 bv = *reinterpret_cast<const f32x4*>(sm.bs + n * 16 + hi * 4);
#pragma unroll
                for (int half = 0; half < 2; ++half) {
                    const int mtl = p * 2 + half;
                    float h0 = fmaxf(fmaf((acc1[mtl][n][0] - mean[half]) * rstd[half], gv[0], bv[0]), 0.f);
                    float h1 = fmaxf(fmaf((acc1[mtl][n][1] - mean[half]) * rstd[half], gv[1], bv[1]), 0.f);
                    float h2 = fmaxf(fmaf((acc1[mtl][n][2] - mean[half]) * rstd[half], gv[2], bv[2]), 0.f);
                    float h3 = fmaxf(fmaf((acc1[mtl][n][3] - mean[half]) * rstd[half], gv[3], bv[3]), 0.f);
                    *reinterpret_cast<uint2*>(hb + ((n >> 1) * 2048 + (n & 1) * 1024
                                                    + half * 256 + hwb)) =
                        make_uint2(pkbf(h0, h1), pkbf(h2, h3));
                }
            }

            // GEMM2 (swapped) on the 32-edge pair: each w2f read feeds 2 MFMAs
            f32x4 a2[2][4];
#pragma unroll
            for (int X = 0; X < 2; ++X)
#pragma unroll
                for (int n2 = 0; n2 < 4; ++n2) a2[X][n2] = zero4;

#pragma unroll
            for (int s = 0; s < 4; ++s) {
                short8 hf0 = *reinterpret_cast<const short8*>(hb + s * 2048 + hi * 512 + lo * 16);
                short8 hf1 = *reinterpret_cast<const short8*>(hb + s * 2048 + hi * 512 + 256 + lo * 16);
                __builtin_amdgcn_s_setprio(1);
#pragma unroll
                for (int n2 = 0; n2 < 4; ++n2) {
                    short8 wa = *reinterpret_cast<const short8*>(sm.w2f + ((s * 4 + n2) * 64 + lane) * 8);
                    a2[0][n2] = __builtin_amdgcn_mfma_f32_16x16x32_bf16(wa, hf0, a2[0][n2], 0, 0, 0);
                    a2[1][n2] = __builtin_amdgcn_mfma_f32_16x16x32_bf16(wa, hf1, a2[1][n2], 0, 0, 0);
                }
                __builtin_amdgcn_s_setprio(0);
            }
            {   // K-step 4: bias row (b2)
                FragU cf; cf.i = make_int4(hi == 0 ? 0x3F80 : 0, 0, 0, 0);
                __builtin_amdgcn_s_setprio(1);
#pragma unroll
                for (int n2 = 0; n2 < 4; ++n2) {
                    short8 wa = *reinterpret_cast<const short8*>(sm.w2f + ((16 + n2) * 64 + lane) * 8);
                    a2[0][n2] = __builtin_amdgcn_mfma_f32_16x16x32_bf16(wa, cf.s, a2[0][n2], 0, 0, 0);
                    a2[1][n2] = __builtin_amdgcn_mfma_f32_16x16x32_bf16(wa, cf.s, a2[1][n2], 0, 0, 0);
                }
                __builtin_amdgcn_s_setprio(0);
            }

            // epilogue: relu, dot W3 (w3v amortized across X), cross-hi reduce, store
            float part0 = 0.f, part1 = 0.f;
#pragma unroll
            for (int n2 = 0; n2 < 4; ++n2) {
                f32x4 w3v = *reinterpret_cast<const f32x4*>(sm.w3s + n2 * 16 + hi * 4);
#pragma unroll
                for (int r = 0; r < 4; ++r) {
                    part0 = fmaf(fmaxf(a2[0][n2][r], 0.f), w3v[r], part0);
                    part1 = fmaf(fmaxf(a2[1][n2][r], 0.f), w3v[r], part1);
                }
            }
            part0 += __shfl_xor(part0, 16); part0 += __shfl_xor(part0, 32);
            part1 += __shfl_xor(part1, 16); part1 += __shfl_xor(part1, 32);
            if (hi == 0) {
                int e0 = tb + (p * 2 + 0) * 16 + lo;
                int e1 = tb + (p * 2 + 1) * 16 + lo;
                if (e0 < E) out[e0] = part0 + b3s;
                if (e1 < E) out[e1] = part1 + b3s;
            }
        }
    }
}

} // namespace

extern "C" void kernel_launch(void* const* d_in, const int* in_sizes, int n_in,
                              void* d_out, int out_size, void* d_ws, size_t ws_size,
                              hipStream_t stream) {
    const float* node_embed = (const float*)d_in[0];
    const int*   eidx       = (const int*)  d_in[1];
    const float* attr       = (const float*)d_in[2];
    const float* W1         = (const float*)d_in[3];
    const float* b1         = (const float*)d_in[4];
    const float* gamma      = (const float*)d_in[5];
    const float* beta       = (const float*)d_in[6];
    const float* W2         = (const float*)d_in[7];
    const float* b2         = (const float*)d_in[8];
    const float* W3         = (const float*)d_in[9];
    const float* b3         = (const float*)d_in[10];
    float* out = (float*)d_out;

    if (ws_size < WS_NEED) return;

    char* ws = (char*)d_ws;
    ushort_t* nbf = (ushort_t*)(ws + NB_OFF);
    ushort_t* w1f = (ushort_t*)(ws + W1F_OFF);
    ushort_t* w2f = (ushort_t*)(ws + W2F_OFF);

    cvt_nodes<<<2048, 256, 0, stream>>>(node_embed, nbf, NNODE * H / 4);
    cvt_wfrag<<<92, 64, 0, stream>>>(W1, b1, W2, b2, w1f, w2f);
    edge_mlp_mfma<<<GRID, 512, 0, stream>>>(nbf, w1f, w2f, eidx, attr,
                                            gamma, beta, W3, b3, out);
}

// Round 12
// 156.424 us; speedup vs baseline: 1.2415x; 1.0161x over previous
//
#include <hip/hip_runtime.h>
#include <hip/hip_bf16.h>

typedef __attribute__((ext_vector_type(8))) short short8;
typedef __attribute__((ext_vector_type(4))) float f32x4;
typedef unsigned short ushort_t;

namespace {

constexpr int H     = 128;
constexpr int E     = 1000000;
constexpr int NNODE = 100000;
constexpr int EB    = 512;                   // edges per tile (8 waves x 64)
constexpr int NTILE = (E + EB - 1) / EB;     // 1954
constexpr int GRID  = 256;                   // persistent: 1 block per CU
constexpr int TPB   = NTILE / GRID;          // 7
constexpr int REM   = NTILE - TPB * GRID;    // 162 blocks do TPB+1 tiles

// d_ws layout
constexpr size_t NB_OFF  = 0;                                  // bf16 nodes: 25.6 MB
constexpr size_t W1F_OFF = (size_t)NNODE * H * 2;
constexpr size_t W1F_SZ  = 72 * 64 * 8 * 2;                    // 73728 B (K=288)
constexpr size_t W2F_OFF = W1F_OFF + W1F_SZ;
constexpr size_t W2F_SZ  = 20 * 64 * 8 * 2;                    // 20480 B (K=160)
constexpr size_t WS_NEED = W2F_OFF + W2F_SZ;

__device__ __forceinline__ ushort_t f2bf(float x) {
    unsigned u = __float_as_uint(x);
    return (ushort_t)((u + 0x7FFFu + ((u >> 16) & 1u)) >> 16);
}
__device__ __forceinline__ unsigned pkbf(float a, float b) {
    __hip_bfloat162 t = __float22bfloat162_rn(make_float2(a, b));
    return *reinterpret_cast<unsigned*>(&t);
}
__device__ __forceinline__ int imin(int a, int b) { return a < b ? a : b; }

union FragU { int4 i; short8 s; };

// ---- prep 1: node_embed fp32 -> bf16 table ----
__global__ void cvt_nodes(const float* __restrict__ src, ushort_t* __restrict__ dst, int n4) {
    int i = blockIdx.x * blockDim.x + threadIdx.x;
    int stride = gridDim.x * blockDim.x;
    for (; i < n4; i += stride) {
        float4 v = reinterpret_cast<const float4*>(src)[i];
        ushort4 o;
        o.x = f2bf(v.x); o.y = f2bf(v.y); o.z = f2bf(v.z); o.w = f2bf(v.w);
        reinterpret_cast<ushort4*>(dst)[i] = o;
    }
}

// ---- prep 2: W1ext (K=288) / W2ext (K=160) -> MFMA fragment layout ----
__global__ void cvt_wfrag(const float* __restrict__ W1, const float* __restrict__ b1,
                          const float* __restrict__ W2, const float* __restrict__ b2,
                          ushort_t* __restrict__ w1f, ushort_t* __restrict__ w2f) {
    int u = blockIdx.x, l = threadIdx.x;
    int lo = l & 15, hi = l >> 4;
    if (u < 72) {                       // W1ext: 9 K-steps x 8 N-tiles
        int s = u >> 3, n = u & 7, col = n * 16 + lo;
#pragma unroll
        for (int j = 0; j < 8; ++j) {
            int kk = s * 32 + hi * 8 + j;
            float v = (kk < 258) ? W1[kk * 128 + col]
                    : (kk == 258 ? b1[col] : 0.f);
            w1f[(u * 64 + l) * 8 + j] = f2bf(v);
        }
    } else {                            // W2ext: 5 K-steps x 4 N-tiles
        int u2 = u - 72;
        int s = u2 >> 2, n = u2 & 3, col = n * 16 + lo;
#pragma unroll
        for (int j = 0; j < 8; ++j) {
            int kk = s * 32 + hi * 8 + j;
            float v = (kk < 128) ? W2[kk * 64 + col]
                    : (kk == 128 ? b2[col] : 0.f);
            w2f[(u2 * 64 + l) * 8 + j] = f2bf(v);
        }
    }
}

// ---- main persistent kernel: 512 threads, 8 waves, 64 edges/wave ----
struct SmemT {
    ushort_t w1f[36864];     // 73728 B
    ushort_t w2f[10240];     // 20480 B
    char     hbuf[65536];    // 8 waves x 8 KB (32-edge pair buffer, fenced)
    float    gs[128], bs[128], w3s[64];
};                           // 161024 B

// VMEM-pin: DS/ALU/MFMA may cross; gather loads may not be sunk to use sites.
#define VPIN() __builtin_amdgcn_sched_barrier(0x38F)

// gather one K-slice (4 subtiles) into a named frag buffer, pinned at issue point
#define GLOAD(dst, nodes, sl)                                                              \
    _Pragma("unroll")                                                                      \
    for (int mt_ = 0; mt_ < 4; ++mt_)                                                      \
        dst[mt_] = *reinterpret_cast<const short8*>(                                       \
            nb + (size_t)nodes[mt_] * H + (sl) * 32 + hi * 8);                             \
    VPIN();

// one GEMM1 K-step: 8 W-fragment reads, each feeding 4 MFMAs.
// NO setprio here (round 12): the per-step setprio intrinsics acted as scheduler
// fences that blocked cross-step ds_read pipelining.
#define KSTEP(fbuf, sidx)                                                                  \
    _Pragma("unroll")                                                                      \
    for (int n_ = 0; n_ < 8; ++n_) {                                                       \
        short8 wa_ = *reinterpret_cast<const short8*>(                                     \
            sm.w1f + (((sidx) * 8 + n_) * 64 + lane) * 8);                                 \
        _Pragma("unroll")                                                                  \
        for (int mt_ = 0; mt_ < 4; ++mt_)                                                  \
            acc1[mt_][n_] = __builtin_amdgcn_mfma_f32_16x16x32_bf16(                       \
                wa_, fbuf[mt_], acc1[mt_][n_], 0, 0, 0);                                   \
    }

__global__ __launch_bounds__(512, 2)
void edge_mlp_mfma(const ushort_t* __restrict__ nb,
                   const ushort_t* __restrict__ w1fg,
                   const ushort_t* __restrict__ w2fg,
                   const int*      __restrict__ eidx,   // [2][E] int32
                   const float*    __restrict__ attr,   // [E][2]
                   const float*    __restrict__ gamma_,
                   const float*    __restrict__ beta_,
                   const float*    __restrict__ W3,
                   const float*    __restrict__ b3,
                   float*          __restrict__ out) {
    __shared__ SmemT sm;
    const int tid = threadIdx.x;
    const int bid = blockIdx.x;

    // ---- stage weights/params ONCE ----
    {
        const uint4* s1 = reinterpret_cast<const uint4*>(w1fg);
        uint4*       d1 = reinterpret_cast<uint4*>(sm.w1f);
        for (int i = tid; i < 4608; i += 512) d1[i] = s1[i];
        const uint4* s2 = reinterpret_cast<const uint4*>(w2fg);
        uint4*       d2 = reinterpret_cast<uint4*>(sm.w2f);
        for (int i = tid; i < 1280; i += 512) d2[i] = s2[i];
    }
    if (tid < 128) { sm.gs[tid] = gamma_[tid]; sm.bs[tid] = beta_[tid]; }
    else if (tid >= 256 && tid < 320) sm.w3s[tid - 256] = W3[tid - 256];
    __syncthreads();   // the only block-wide barrier

    const int wid = tid >> 6;
    const int lane = tid & 63;
    const int lo = lane & 15, hi = lane >> 4;
    const int ebl = wid * 64;
    const int nk = (bid < REM) ? TPB + 1 : TPB;
    char* hb = sm.hbuf + wid * 8192;
    const float2* attr2 = reinterpret_cast<const float2*>(attr);
    const float b3s = b3[0];
    const f32x4 zero4 = {0.f, 0.f, 0.f, 0.f};

    // h layout (32-edge pair buffer): element (edge e'=0..31, col) at byte
    //   (col>>5)*2048 + ((col>>3)&3)*512 + e'*16 + (col&7)*2
    const int hwb = lo * 16 + (hi & 1) * 8 + (hi >> 1) * 512;

    // ---- index state: ci/cj = tile-k indices, xi/xj = tile-(k+1) ----
    int ci[4], cj[4], xi[4], xj[4];
    {
        int tb0 = bid * EB + ebl;
#pragma unroll
        for (int mt = 0; mt < 4; ++mt) {
            int e = imin(tb0 + mt * 16 + lo, E - 1);
            ci[mt] = eidx[e]; cj[mt] = eidx[E + e];
        }
    }
    // 2-deep rolling gather buffers (f2 deleted -> 32 VGPRs freed for the
    // scheduler to pipeline W1 ds_reads across K-steps)
    short8 f0[4], f1[4];
    GLOAD(f0, ci, 0); GLOAD(f1, ci, 1);
    {
        int tb1 = (bid + imin(1, nk - 1) * GRID) * EB + ebl;
#pragma unroll
        for (int mt = 0; mt < 4; ++mt) {
            int e = imin(tb1 + mt * 16 + lo, E - 1);
            xi[mt] = eidx[e]; xj[mt] = eidx[E + e];
        }
    }

    for (int k = 0; k < nk; ++k) {
        const int tb = (bid + k * GRID) * EB + ebl;

        float2 av[4];
#pragma unroll
        for (int mt = 0; mt < 4; ++mt)
            av[mt] = attr2[imin(tb + mt * 16 + lo, E - 1)];
        VPIN();

        // ---- GEMM1 (swapped): acc[subtile][feat-tile], K=288, 2-deep rolling gathers ----
        f32x4 acc1[4][8];
#pragma unroll
        for (int mt = 0; mt < 4; ++mt)
#pragma unroll
            for (int n = 0; n < 8; ++n) acc1[mt][n] = zero4;

        KSTEP(f0, 0); GLOAD(f0, ci, 2);
        KSTEP(f1, 1); GLOAD(f1, ci, 3);
        KSTEP(f0, 2); GLOAD(f0, cj, 0);
        KSTEP(f1, 3); GLOAD(f1, cj, 1);
        KSTEP(f0, 4); GLOAD(f0, cj, 2);
        KSTEP(f1, 5); GLOAD(f1, cj, 3);
        KSTEP(f0, 6);
        KSTEP(f1, 7);
        {   // K-step 8: attr0, attr1, bias(1.0) rows
            FragU fa[4];
#pragma unroll
            for (int mt = 0; mt < 4; ++mt)
                fa[mt].i = make_int4(hi == 0 ? (int)pkbf(av[mt].x, av[mt].y) : 0,
                                     hi == 0 ? 0x3F80 : 0, 0, 0);
#pragma unroll
            for (int n = 0; n < 8; ++n) {
                short8 wa = *reinterpret_cast<const short8*>(sm.w1f + ((64 + n) * 64 + lane) * 8);
#pragma unroll
                for (int mt = 0; mt < 4; ++mt)
                    acc1[mt][n] = __builtin_amdgcn_mfma_f32_16x16x32_bf16(wa, fa[mt].s, acc1[mt][n], 0, 0, 0);
            }
        }

        // ---- rotate indices; issue next tile's first gather slices now ----
#pragma unroll
        for (int mt = 0; mt < 4; ++mt) { ci[mt] = xi[mt]; cj[mt] = xj[mt]; }
        GLOAD(f0, ci, 0); GLOAD(f1, ci, 1);
        {
            int t2 = imin(k + 2, nk - 1);
            int tb2 = (bid + t2 * GRID) * EB + ebl;
#pragma unroll
            for (int mt = 0; mt < 4; ++mt) {
                int e = imin(tb2 + mt * 16 + lo, E - 1);
                xi[mt] = eidx[e]; xj[mt] = eidx[E + e];
            }
            VPIN();
        }

        // ---- phase 2: two 32-edge pairs (write-all-h, then GEMM2) ----
#pragma unroll
        for (int p = 0; p < 2; ++p) {
            // WAR fence: previous pair's GEMM2 ds_reads must complete before
            // overwriting the shared h buffer (rule #18: pin with sched_barrier).
            asm volatile("s_waitcnt lgkmcnt(0)" ::: "memory");
            __builtin_amdgcn_sched_barrier(0);

            // LN stats for this pair's two halves (chains overlap)
            float mean[2], rstd[2];
#pragma unroll
            for (int half = 0; half < 2; ++half) {
                const int mtl = p * 2 + half;
                float s1 = 0.f, s2 = 0.f;
#pragma unroll
                for (int n = 0; n < 8; ++n)
#pragma unroll
                    for (int r = 0; r < 4; ++r) {
                        float x = acc1[mtl][n][r];
                        s1 += x; s2 = fmaf(x, x, s2);
                    }
                s1 += __shfl_xor(s1, 16); s1 += __shfl_xor(s1, 32);
                s2 += __shfl_xor(s2, 16); s2 += __shfl_xor(s2, 32);
                float mu = s1 * (1.f / 128.f);
                float var = s2 * (1.f / 128.f) - mu * mu;
                mean[half] = mu;
                rstd[half] = rsqrtf(var + 1e-5f);
            }

            // h-writes: n outer so gv/bv amortize across the two halves
#pragma unroll
            for (int n = 0; n < 8; ++n) {
                f32x4 gv = *reinterpret_cast<const f32x4*>(sm.gs + n * 16 + hi * 4);
                f32x4 bv = *reinterpret_cast<const f32x4*>(sm.bs + n * 16 + hi * 4);
#pragma unroll
                for (int half = 0; half < 2; ++half) {
                    const int mtl = p * 2 + half;
                    float h0 = fmaxf(fmaf((acc1[mtl][n][0] - mean[half]) * rstd[half], gv[0], bv[0]), 0.f);
                    float h1 = fmaxf(fmaf((acc1[mtl][n][1] - mean[half]) * rstd[half], gv[1], bv[1]), 0.f);
                    float h2 = fmaxf(fmaf((acc1[mtl][n][2] - mean[half]) * rstd[half], gv[2], bv[2]), 0.f);
                    float h3 = fmaxf(fmaf((acc1[mtl][n][3] - mean[half]) * rstd[half], gv[3], bv[3]), 0.f);
                    *reinterpret_cast<uint2*>(hb + ((n >> 1) * 2048 + (n & 1) * 1024
                                                    + half * 256 + hwb)) =
                        make_uint2(pkbf(h0, h1), pkbf(h2, h3));
                }
            }

            // GEMM2 (swapped) on the 32-edge pair: each w2f read feeds 2 MFMAs
            f32x4 a2[2][4];
#pragma unroll
            for (int X = 0; X < 2; ++X)
#pragma unroll
                for (int n2 = 0; n2 < 4; ++n2) a2[X][n2] = zero4;

#pragma unroll
            for (int s = 0; s < 4; ++s) {
                short8 hf0 = *reinterpret_cast<const short8*>(hb + s * 2048 + hi * 512 + lo * 16);
                short8 hf1 = *reinterpret_cast<const short8*>(hb + s * 2048 + hi * 512 + 256 + lo * 16);
                __builtin_amdgcn_s_setprio(1);
#pragma unroll
                for (int n2 = 0; n2 < 4; ++n2) {
                    short8 wa = *reinterpret_cast<const short8*>(sm.w2f + ((s * 4 + n2) * 64 + lane) * 8);
                    a2[0][n2] = __builtin_amdgcn_mfma_f32_16x16x32_bf16(wa, hf0, a2[0][n2], 0, 0, 0);
                    a2[1][n2] = __builtin_amdgcn_mfma_f32_16x16x32_bf16(wa, hf1, a2[1][n2], 0, 0, 0);
                }
                __builtin_amdgcn_s_setprio(0);
            }
            {   // K-step 4: bias row (b2)
                FragU cf; cf.i = make_int4(hi == 0 ? 0x3F80 : 0, 0, 0, 0);
                __builtin_amdgcn_s_setprio(1);
#pragma unroll
                for (int n2 = 0; n2 < 4; ++n2) {
                    short8 wa = *reinterpret_cast<const short8*>(sm.w2f + ((16 + n2) * 64 + lane) * 8);
                    a2[0][n2] = __builtin_amdgcn_mfma_f32_16x16x32_bf16(wa, cf.s, a2[0][n2], 0, 0, 0);
                    a2[1][n2] = __builtin_amdgcn_mfma_f32_16x16x32_bf16(wa, cf.s, a2[1][n2], 0, 0, 0);
                }
                __builtin_amdgcn_s_setprio(0);
            }

            // epilogue: relu, dot W3 (w3v amortized across X), cross-hi reduce, store
            float part0 = 0.f, part1 = 0.f;
#pragma unroll
            for (int n2 = 0; n2 < 4; ++n2) {
                f32x4 w3v = *reinterpret_cast<const f32x4*>(sm.w3s + n2 * 16 + hi * 4);
#pragma unroll
                for (int r = 0; r < 4; ++r) {
                    part0 = fmaf(fmaxf(a2[0][n2][r], 0.f), w3v[r], part0);
                    part1 = fmaf(fmaxf(a2[1][n2][r], 0.f), w3v[r], part1);
                }
            }
            part0 += __shfl_xor(part0, 16); part0 += __shfl_xor(part0, 32);
            part1 += __shfl_xor(part1, 16); part1 += __shfl_xor(part1, 32);
            if (hi == 0) {
                int e0 = tb + (p * 2 + 0) * 16 + lo;
                int e1 = tb + (p * 2 + 1) * 16 + lo;
                if (e0 < E) out[e0] = part0 + b3s;
                if (e1 < E) out[e1] = part1 + b3s;
            }
        }
    }
}

} // namespace

extern "C" void kernel_launch(void* const* d_in, const int* in_sizes, int n_in,
                              void* d_out, int out_size, void* d_ws, size_t ws_size,
                              hipStream_t stream) {
    const float* node_embed = (const float*)d_in[0];
    const int*   eidx       = (const int*)  d_in[1];
    const float* attr       = (const float*)d_in[2];
    const float* W1         = (const float*)d_in[3];
    const float* b1         = (const float*)d_in[4];
    const float* gamma      = (const float*)d_in[5];
    const float* beta       = (const float*)d_in[6];
    const float* W2         = (const float*)d_in[7];
    const float* b2         = (const float*)d_in[8];
    const float* W3         = (const float*)d_in[9];
    const float* b3         = (const float*)d_in[10];
    float* out = (float*)d_out;

    if (ws_size < WS_NEED) return;

    char* ws = (char*)d_ws;
    ushort_t* nbf = (ushort_t*)(ws + NB_OFF);
    ushort_t* w1f = (ushort_t*)(ws + W1F_OFF);
    ushort_t* w2f = (ushort_t*)(ws + W2F_OFF);

    cvt_nodes<<<2048, 256, 0, stream>>>(node_embed, nbf, NNODE * H / 4);
    cvt_wfrag<<<92, 64, 0, stream>>>(W1, b1, W2, b2, w1f, w2f);
    edge_mlp_mfma<<<GRID, 512, 0, stream>>>(nbf, w1f, w2f, eidx, attr,
                                            gamma, beta, W3, b3, out);
}

// Round 13
// 148.167 us; speedup vs baseline: 1.3107x; 1.0557x over previous
//
#include <hip/hip_runtime.h>
#include <hip/hip_bf16.h>
#include <hip/hip_fp16.h>

typedef __attribute__((ext_vector_type(8))) short short8;
typedef __attribute__((ext_vector_type(4))) float f32x4;
typedef unsigned short ushort_t;

namespace {

constexpr int H     = 128;
constexpr int E     = 1000000;
constexpr int NNODE = 100000;
constexpr int EB    = 512;                   // edges per tile (8 waves x 64)
constexpr int NTILE = (E + EB - 1) / EB;     // 1954
constexpr int GRID  = 256;
constexpr int TPB   = NTILE / GRID;          // 7
constexpr int REM   = NTILE - TPB * GRID;

// d_ws layout: atab fp16 [NNODE][256] (Ai | Aj), then W1/W2 fragment tables
constexpr size_t AT_OFF  = 0;
constexpr size_t AT_SZ   = (size_t)NNODE * 256 * 2;   // 51,200,000 B
constexpr size_t W1F_OFF = AT_SZ;
constexpr size_t W1F_SZ  = 64 * 64 * 8 * 2;           // 65536 B (K=256, 8 steps x 8 ntiles)
constexpr size_t W2F_OFF = W1F_OFF + W1F_SZ;
constexpr size_t W2F_SZ  = 20 * 64 * 8 * 2;           // 20480 B (K=160)
constexpr size_t WS_NEED = W2F_OFF + W2F_SZ;

__device__ __forceinline__ ushort_t f2bf(float x) {
    unsigned u = __float_as_uint(x);
    return (ushort_t)((u + 0x7FFFu + ((u >> 16) & 1u)) >> 16);
}
__device__ __forceinline__ unsigned pkbf(float a, float b) {
    __hip_bfloat162 t = __float22bfloat162_rn(make_float2(a, b));
    return *reinterpret_cast<unsigned*>(&t);
}
__device__ __forceinline__ unsigned pkhf(float a, float b) {
    __half2 t = __float22half2_rn(make_float2(a, b));
    return *reinterpret_cast<unsigned*>(&t);
}
__device__ __forceinline__ int imin(int a, int b) { return a < b ? a : b; }

union FragU { int4 i; short8 s; };
union HalfU { short8 s; __half h[8]; };

// ---- prep 1: W1 (rows 0..255) / W2ext (K=160) -> MFMA A-fragment layout ----
__global__ void cvt_wfrag(const float* __restrict__ W1, const float* __restrict__ W2,
                          const float* __restrict__ b2,
                          ushort_t* __restrict__ w1f, ushort_t* __restrict__ w2f) {
    int u = blockIdx.x, l = threadIdx.x;
    int lo = l & 15, hi = l >> 4;
    if (u < 64) {                       // W1: 8 K-steps x 8 N-tiles (rows 0..255 only)
        int s = u >> 3, n = u & 7, col = n * 16 + lo;
#pragma unroll
        for (int j = 0; j < 8; ++j) {
            int kk = s * 32 + hi * 8 + j;           // 0..255
            w1f[(u * 64 + l) * 8 + j] = f2bf(W1[kk * 128 + col]);
        }
    } else {                            // W2ext: 5 K-steps x 4 N-tiles
        int u2 = u - 64;
        int s = u2 >> 2, n = u2 & 3, col = n * 16 + lo;
#pragma unroll
        for (int j = 0; j < 8; ++j) {
            int kk = s * 32 + hi * 8 + j;
            float v = (kk < 128) ? W2[kk * 64 + col]
                    : (kk == 128 ? b2[col] : 0.f);
            w2f[(u2 * 64 + l) * 8 + j] = f2bf(v);
        }
    }
}

// ---- prep 2: A-tables. Ai = node_embed . W1[0:128], Aj = node_embed . W1[128:256]
//      atab[node][256] fp16 = [Ai(128) | Aj(128)] ----
struct PrepSm { ushort_t w1f[32768]; };   // 64 KB

__global__ __launch_bounds__(512, 2)
void build_atab(const float* __restrict__ ne, const ushort_t* __restrict__ w1fg,
                ushort_t* __restrict__ atab) {
    __shared__ PrepSm sm;
    const int tid = threadIdx.x;
    {
        const uint4* s1 = reinterpret_cast<const uint4*>(w1fg);
        uint4*       d1 = reinterpret_cast<uint4*>(sm.w1f);
#pragma unroll
        for (int i = 0; i < 8; ++i) d1[i * 512 + tid] = s1[i * 512 + tid];
    }
    __syncthreads();

    const int wid = tid >> 6, lane = tid & 63;
    const int lo = lane & 15, hi = lane >> 4;
    const int nbase = blockIdx.x * 512 + wid * 64;
    const f32x4 z4 = {0.f, 0.f, 0.f, 0.f};

    // node rows as bf16 B-fragments (same rounding as the old GEMM1 path)
    short8 nf[4][4];
#pragma unroll
    for (int mt = 0; mt < 4; ++mt) {
        int node = imin(nbase + mt * 16 + lo, NNODE - 1);
        const float* row = ne + (size_t)node * H;
#pragma unroll
        for (int s = 0; s < 4; ++s) {
            f32x4 a = *reinterpret_cast<const f32x4*>(row + s * 32 + hi * 8);
            f32x4 b = *reinterpret_cast<const f32x4*>(row + s * 32 + hi * 8 + 4);
            FragU f;
            f.i = make_int4((int)pkbf(a[0], a[1]), (int)pkbf(a[2], a[3]),
                            (int)pkbf(b[0], b[1]), (int)pkbf(b[2], b[3]));
            nf[mt][s] = f.s;
        }
    }

#pragma unroll
    for (int X = 0; X < 2; ++X) {       // X=0: Wi (steps 0..3), X=1: Wj (steps 4..7)
        f32x4 acc[4][8];
#pragma unroll
        for (int mt = 0; mt < 4; ++mt)
#pragma unroll
            for (int n = 0; n < 8; ++n) acc[mt][n] = z4;
#pragma unroll
        for (int s = 0; s < 4; ++s)
#pragma unroll
            for (int n = 0; n < 8; ++n) {
                short8 wa = *reinterpret_cast<const short8*>(
                    sm.w1f + (((X * 4 + s) * 8 + n) * 64 + lane) * 8);
#pragma unroll
                for (int mt = 0; mt < 4; ++mt)
                    acc[mt][n] = __builtin_amdgcn_mfma_f32_16x16x32_bf16(wa, nf[mt][s], acc[mt][n], 0, 0, 0);
            }
        // store: D[row=feat n*16+hi*4+r][col=node lo] -> fp16 pairs, 8B per (mt,n)
#pragma unroll
        for (int mt = 0; mt < 4; ++mt) {
            int node = nbase + mt * 16 + lo;
            if (node < NNODE) {
                ushort_t* dst = atab + (size_t)node * 256 + X * 128;
#pragma unroll
                for (int n = 0; n < 8; ++n) {
                    uint2 v = make_uint2(pkhf(acc[mt][n][0], acc[mt][n][1]),
                                         pkhf(acc[mt][n][2], acc[mt][n][3]));
                    *reinterpret_cast<uint2*>(dst + n * 16 + hi * 4) = v;
                }
            }
        }
    }
}

// ---- main persistent kernel: 512 threads, 8 waves, 64 edges/wave, NO hbuf ----
struct SmemT {
    ushort_t w2f[10240];                 // 20480 B
    float b1s[128], t0s[128], t1s[128], gs[128], bs[128], w3s[64];
};                                       // ~23 KB

#define VPIN() __builtin_amdgcn_sched_barrier(0x38F)

#define GATHI(dst, nodes)                                                                  \
    _Pragma("unroll")                                                                      \
    for (int mt_ = 0; mt_ < 4; ++mt_)                                                      \
        _Pragma("unroll")                                                                  \
        for (int s_ = 0; s_ < 4; ++s_)                                                     \
            dst[mt_][s_] = *reinterpret_cast<const short8*>(                               \
                atab + (size_t)nodes[mt_] * 256 + s_ * 32 + hi * 8);                       \
    VPIN();

#define GATHJ(dst, nodes)                                                                  \
    _Pragma("unroll")                                                                      \
    for (int mt_ = 0; mt_ < 4; ++mt_)                                                      \
        _Pragma("unroll")                                                                  \
        for (int s_ = 0; s_ < 4; ++s_)                                                     \
            dst[mt_][s_] = *reinterpret_cast<const short8*>(                               \
                atab + (size_t)nodes[mt_] * 256 + 128 + s_ * 32 + hi * 8);                 \
    VPIN();

__global__ __launch_bounds__(512, 2)
void edge_mlp_mfma(const ushort_t* __restrict__ atab,
                   const ushort_t* __restrict__ w2fg,
                   const int*      __restrict__ eidx,   // [2][E] int32
                   const float*    __restrict__ attr,   // [E][2]
                   const float*    __restrict__ W1,     // rows 256/257 (attr rows)
                   const float*    __restrict__ b1,
                   const float*    __restrict__ gamma_,
                   const float*    __restrict__ beta_,
                   const float*    __restrict__ W3,
                   const float*    __restrict__ b3,
                   float*          __restrict__ out) {
    __shared__ SmemT sm;
    const int tid = threadIdx.x;
    const int bid = blockIdx.x;

    {
        const uint4* s2 = reinterpret_cast<const uint4*>(w2fg);
        uint4*       d2 = reinterpret_cast<uint4*>(sm.w2f);
        for (int i = tid; i < 1280; i += 512) d2[i] = s2[i];
    }
    if (tid < 128) {
        sm.b1s[tid] = b1[tid];
        sm.t0s[tid] = W1[256 * 128 + tid];
        sm.t1s[tid] = W1[257 * 128 + tid];
        sm.gs[tid]  = gamma_[tid];
        sm.bs[tid]  = beta_[tid];
        if (tid < 64) sm.w3s[tid] = W3[tid];
    }
    __syncthreads();   // the only block-wide barrier

    const int wid = tid >> 6;
    const int lane = tid & 63;
    const int lo = lane & 15, hi = lane >> 4;
    const int ebl = wid * 64;
    const int nk = (bid < REM) ? TPB + 1 : TPB;
    const float2* attr2 = reinterpret_cast<const float2*>(attr);
    const float b3s = b3[0];
    const f32x4 zero4 = {0.f, 0.f, 0.f, 0.f};

    int ci[4], cj[4], xi[4], xj[4];
    {
        int tb0 = bid * EB + ebl;
#pragma unroll
        for (int mt = 0; mt < 4; ++mt) {
            int e = imin(tb0 + mt * 16 + lo, E - 1);
            ci[mt] = eidx[e]; cj[mt] = eidx[E + e];
        }
    }
    short8 ai[4][4], aj[4][4];
    GATHI(ai, ci);
    GATHJ(aj, cj);
    {
        int tb1 = (bid + imin(1, nk - 1) * GRID) * EB + ebl;
#pragma unroll
        for (int mt = 0; mt < 4; ++mt) {
            int e = imin(tb1 + mt * 16 + lo, E - 1);
            xi[mt] = eidx[e]; xj[mt] = eidx[E + e];
        }
    }

    for (int k = 0; k < nk; ++k) {
        const int tb = (bid + k * GRID) * EB + ebl;

        float2 av[4];
#pragma unroll
        for (int mt = 0; mt < 4; ++mt)
            av[mt] = attr2[imin(tb + mt * 16 + lo, E - 1)];

        // ---- x = Ai[i] + b1 + attr.(t0,t1)  (i-side; frees ai) ----
        f32x4 x[4][4][2];
#pragma unroll
        for (int s = 0; s < 4; ++s) {
            f32x4 b1a = *reinterpret_cast<const f32x4*>(sm.b1s + s * 32 + hi * 8);
            f32x4 b1b = *reinterpret_cast<const f32x4*>(sm.b1s + s * 32 + hi * 8 + 4);
            f32x4 t0a = *reinterpret_cast<const f32x4*>(sm.t0s + s * 32 + hi * 8);
            f32x4 t0b = *reinterpret_cast<const f32x4*>(sm.t0s + s * 32 + hi * 8 + 4);
            f32x4 t1a = *reinterpret_cast<const f32x4*>(sm.t1s + s * 32 + hi * 8);
            f32x4 t1b = *reinterpret_cast<const f32x4*>(sm.t1s + s * 32 + hi * 8 + 4);
#pragma unroll
            for (int mt = 0; mt < 4; ++mt) {
                HalfU ui; ui.s = ai[mt][s];
#pragma unroll
                for (int q = 0; q < 2; ++q) {
                    f32x4 bb = q ? b1b : b1a;
                    f32x4 w0 = q ? t0b : t0a;
                    f32x4 w1 = q ? t1b : t1a;
#pragma unroll
                    for (int r = 0; r < 4; ++r) {
                        float v = __half2float(ui.h[q * 4 + r]) + bb[r];
                        v = fmaf(av[mt].x, w0[r], v);
                        v = fmaf(av[mt].y, w1[r], v);
                        x[mt][s][q][r] = v;
                    }
                }
            }
        }
        // ---- x += Aj[j]  (frees aj) ----
#pragma unroll
        for (int s = 0; s < 4; ++s)
#pragma unroll
            for (int mt = 0; mt < 4; ++mt) {
                HalfU uj; uj.s = aj[mt][s];
#pragma unroll
                for (int q = 0; q < 2; ++q)
#pragma unroll
                    for (int r = 0; r < 4; ++r)
                        x[mt][s][q][r] += __half2float(uj.h[q * 4 + r]);
            }

        // ---- rotate indices; prefetch next tile's i-side into freed ai regs ----
#pragma unroll
        for (int mt = 0; mt < 4; ++mt) { ci[mt] = xi[mt]; cj[mt] = xj[mt]; }
        GATHI(ai, ci);

        // ---- LayerNorm stats (per edge-subtile; 2 shuffles each) ----
        float mean[4], rstd[4];
#pragma unroll
        for (int mt = 0; mt < 4; ++mt) {
            float s1 = 0.f, s2 = 0.f;
#pragma unroll
            for (int s = 0; s < 4; ++s)
#pragma unroll
                for (int q = 0; q < 2; ++q)
#pragma unroll
                    for (int r = 0; r < 4; ++r) {
                        float v = x[mt][s][q][r];
                        s1 += v; s2 = fmaf(v, v, s2);
                    }
            s1 += __shfl_xor(s1, 16); s1 += __shfl_xor(s1, 32);
            s2 += __shfl_xor(s2, 16); s2 += __shfl_xor(s2, 32);
            float mu = s1 * (1.f / 128.f);
            float var = s2 * (1.f / 128.f) - mu * mu;
            mean[mt] = mu;
            rstd[mt] = rsqrtf(var + 1e-5f);
        }

        // ---- h = relu(LN(x)) packed to bf16 IN REGISTERS (already B-frag layout) ----
        short8 hfr[4][4];
#pragma unroll
        for (int s = 0; s < 4; ++s) {
            f32x4 ga = *reinterpret_cast<const f32x4*>(sm.gs + s * 32 + hi * 8);
            f32x4 gb = *reinterpret_cast<const f32x4*>(sm.gs + s * 32 + hi * 8 + 4);
            f32x4 ba = *reinterpret_cast<const f32x4*>(sm.bs + s * 32 + hi * 8);
            f32x4 bb = *reinterpret_cast<const f32x4*>(sm.bs + s * 32 + hi * 8 + 4);
#pragma unroll
            for (int mt = 0; mt < 4; ++mt) {
                float hv[8];
#pragma unroll
                for (int q = 0; q < 2; ++q) {
                    f32x4 g = q ? gb : ga;
                    f32x4 b = q ? bb : ba;
#pragma unroll
                    for (int r = 0; r < 4; ++r)
                        hv[q * 4 + r] = fmaxf(
                            fmaf((x[mt][s][q][r] - mean[mt]) * rstd[mt], g[r], b[r]), 0.f);
                }
                FragU f;
                f.i = make_int4((int)pkbf(hv[0], hv[1]), (int)pkbf(hv[2], hv[3]),
                                (int)pkbf(hv[4], hv[5]), (int)pkbf(hv[6], hv[7]));
                hfr[mt][s] = f.s;
            }
        }

        // ---- GEMM2 (swapped): each w2f read feeds 4 MFMAs (all subtiles) ----
        f32x4 a2[4][4];
#pragma unroll
        for (int mt = 0; mt < 4; ++mt)
#pragma unroll
            for (int n2 = 0; n2 < 4; ++n2) a2[mt][n2] = zero4;

#pragma unroll
        for (int s = 0; s < 4; ++s) {
            __builtin_amdgcn_s_setprio(1);
#pragma unroll
            for (int n2 = 0; n2 < 4; ++n2) {
                short8 wa = *reinterpret_cast<const short8*>(sm.w2f + ((s * 4 + n2) * 64 + lane) * 8);
#pragma unroll
                for (int mt = 0; mt < 4; ++mt)
                    a2[mt][n2] = __builtin_amdgcn_mfma_f32_16x16x32_bf16(wa, hfr[mt][s], a2[mt][n2], 0, 0, 0);
            }
            __builtin_amdgcn_s_setprio(0);
        }
        {   // K-step 4: bias row (b2)
            FragU cf; cf.i = make_int4(hi == 0 ? 0x3F80 : 0, 0, 0, 0);
            __builtin_amdgcn_s_setprio(1);
#pragma unroll
            for (int n2 = 0; n2 < 4; ++n2) {
                short8 wa = *reinterpret_cast<const short8*>(sm.w2f + ((16 + n2) * 64 + lane) * 8);
#pragma unroll
                for (int mt = 0; mt < 4; ++mt)
                    a2[mt][n2] = __builtin_amdgcn_mfma_f32_16x16x32_bf16(wa, cf.s, a2[mt][n2], 0, 0, 0);
            }
            __builtin_amdgcn_s_setprio(0);
        }

        // ---- epilogue: relu, dot W3 (amortized across all 4 subtiles), store ----
        float part[4] = {0.f, 0.f, 0.f, 0.f};
#pragma unroll
        for (int n2 = 0; n2 < 4; ++n2) {
            f32x4 w3v = *reinterpret_cast<const f32x4*>(sm.w3s + n2 * 16 + hi * 4);
#pragma unroll
            for (int mt = 0; mt < 4; ++mt)
#pragma unroll
                for (int r = 0; r < 4; ++r)
                    part[mt] = fmaf(fmaxf(a2[mt][n2][r], 0.f), w3v[r], part[mt]);
        }
#pragma unroll
        for (int mt = 0; mt < 4; ++mt) {
            part[mt] += __shfl_xor(part[mt], 16);
            part[mt] += __shfl_xor(part[mt], 32);
        }
        if (hi == 0) {
#pragma unroll
            for (int mt = 0; mt < 4; ++mt) {
                int e = tb + mt * 16 + lo;
                if (e < E) out[e] = part[mt] + b3s;
            }
        }

        // ---- prefetch next tile's j-side; indices for tile k+2 ----
        GATHJ(aj, cj);
        {
            int t2 = imin(k + 2, nk - 1);
            int tb2 = (bid + t2 * GRID) * EB + ebl;
#pragma unroll
            for (int mt = 0; mt < 4; ++mt) {
                int e = imin(tb2 + mt * 16 + lo, E - 1);
                xi[mt] = eidx[e]; xj[mt] = eidx[E + e];
            }
            VPIN();
        }
    }
}

} // namespace

extern "C" void kernel_launch(void* const* d_in, const int* in_sizes, int n_in,
                              void* d_out, int out_size, void* d_ws, size_t ws_size,
                              hipStream_t stream) {
    const float* node_embed = (const float*)d_in[0];
    const int*   eidx       = (const int*)  d_in[1];
    const float* attr       = (const float*)d_in[2];
    const float* W1         = (const float*)d_in[3];
    const float* b1         = (const float*)d_in[4];
    const float* gamma      = (const float*)d_in[5];
    const float* beta       = (const float*)d_in[6];
    const float* W2         = (const float*)d_in[7];
    const float* b2         = (const float*)d_in[8];
    const float* W3         = (const float*)d_in[9];
    const float* b3         = (const float*)d_in[10];
    float* out = (float*)d_out;

    if (ws_size < WS_NEED) return;

    char* ws = (char*)d_ws;
    ushort_t* atab = (ushort_t*)(ws + AT_OFF);
    ushort_t* w1f  = (ushort_t*)(ws + W1F_OFF);
    ushort_t* w2f  = (ushort_t*)(ws + W2F_OFF);

    cvt_wfrag<<<84, 64, 0, stream>>>(W1, W2, b2, w1f, w2f);
    build_atab<<<(NNODE + 511) / 512, 512, 0, stream>>>(node_embed, w1f, atab);
    edge_mlp_mfma<<<GRID, 512, 0, stream>>>(atab, w2f, eidx, attr, W1, b1,
                                            gamma, beta, W3, b3, out);
}